// Round 12
// baseline (331.301 us; speedup 1.0000x reference)
//
#include <hip/hip_runtime.h>
#include <math.h>

#define N_NODES 100000
#define N_EDGES 800000
#define D_IN    64
#define HC      128   // H*C
#define CAP     48    // max in-degree slots (Poisson(8): P(>48) ~ 0)

#define GEMM_BLOCKS 1563                 // ceil(100000/64)
#define FUSED_BLOCKS (3 * GEMM_BLOCKS)   // bid%3==2 -> gemm, else scatter

typedef short bf16x8 __attribute__((ext_vector_type(8)));   // 8 bf16 = 4 VGPR
typedef float f32x4  __attribute__((ext_vector_type(4)));
typedef float f32x2  __attribute__((ext_vector_type(2)));

// ---- CDNA packed fp32 (VOP3P, full rate; gfx950 has add/mul/fma ONLY) ----
__device__ __forceinline__ f32x2 pk_add(f32x2 a, f32x2 b) {
    f32x2 d; asm("v_pk_add_f32 %0, %1, %2" : "=v"(d) : "v"(a), "v"(b)); return d;
}
__device__ __forceinline__ f32x2 pk_mul(f32x2 a, f32x2 b) {
    f32x2 d; asm("v_pk_mul_f32 %0, %1, %2" : "=v"(d) : "v"(a), "v"(b)); return d;
}
__device__ __forceinline__ f32x2 pk_fma(f32x2 a, f32x2 b, f32x2 c) {
    f32x2 d; asm("v_pk_fma_f32 %0, %1, %2, %3" : "=v"(d) : "v"(a), "v"(b), "v"(c)); return d;
}
// |x| per half: two full-rate v_and_b32 (no packed max on gfx950)
__device__ __forceinline__ f32x2 pk_abs(f32x2 a) {
    f32x2 d; d[0] = fabsf(a[0]); d[1] = fabsf(a[1]); return d;
}

// tanh-approx gelu (jax.nn.gelu default approximate=True)
__device__ __forceinline__ float gelu_f(float x) {
    float x3 = x * x * x;
    float y  = 0.7978845608028654f * (x + 0.044715f * x3);
    float t = 1.0f - 2.0f / (__expf(2.0f * y) + 1.0f);
    return 0.5f * x * (1.0f + t);
}

// sum across a 16-lane row via DPP row_ror (pure VALU, no ds_swizzle)
__device__ __forceinline__ float red16(float x) {
    x += __int_as_float(__builtin_amdgcn_mov_dpp(__float_as_int(x), 0x128, 0xF, 0xF, true)); // ror:8
    x += __int_as_float(__builtin_amdgcn_mov_dpp(__float_as_int(x), 0x124, 0xF, 0xF, true)); // ror:4
    x += __int_as_float(__builtin_amdgcn_mov_dpp(__float_as_int(x), 0x122, 0xF, 0xF, true)); // ror:2
    x += __int_as_float(__builtin_amdgcn_mov_dpp(__float_as_int(x), 0x121, 0xF, 0xF, true)); // ror:1
    return x;
}

// split fp32 -> bf16 hi (rne) + bf16 lo (rne of residual); x = h + l + O(2^-18 x)
__device__ __forceinline__ void bf16split(float x, unsigned short& h, unsigned short& l) {
    unsigned b  = __float_as_uint(x);
    unsigned hb = (b + 0x7FFFu + ((b >> 16) & 1u)) & 0xFFFF0000u;
    h = (unsigned short)(hb >> 16);
    float lo = x - __uint_as_float(hb);
    unsigned c = __float_as_uint(lo);
    l = (unsigned short)((c + 0x7FFFu + ((c >> 16) & 1u)) >> 16);
}

// ---------------- W prep: lane-ordered bf16 hi/lo ---------------------------
// WB3[layer][w][nt][kh][lane][8] = exactly the consumption order of wave w's
// B-fragments -> every B-frag load in the gemm is 64 lanes x contiguous 16B
// = one coalesced 1KB request.
__global__ __launch_bounds__(256) void wprep_kernel(
    const float* __restrict__ Wl, const float* __restrict__ Wr,
    unsigned short* __restrict__ WBh, unsigned short* __restrict__ WBlo) {
    int g = blockIdx.x * 256 + threadIdx.x;       // 0..32767
    int layer = g >> 14;
    int rem   = g & 16383;        // (((w*4+nt)*2+kh)*64 + lane)*8 + j
    int j    = rem & 7;
    int idx  = rem >> 3;
    int lane = idx & 63;
    int kh   = (idx >> 6) & 1;
    int nt   = (idx >> 7) & 3;
    int w    = (idx >> 9) & 3;
    int col  = w * 64 + nt * 16 + (lane & 15);    // 0..255 (128+ = Wr)
    int k    = kh * 32 + (lane >> 4) * 8 + j;
    const float* W = (col < 128) ? Wl : Wr;
    float x = W[layer * 8192 + k * HC + (col & 127)];
    unsigned short h, l;
    bf16split(x, h, l);
    WBh[g] = h; WBlo[g] = l;
}

// ---------------- fused split-bf16 MFMA GEMM (+ scatter role) ---------------
// [N,64]@[64,256]: block = 64 nodes x 256 ch, 4 waves; wave w = 64 ch
// (w<2 -> XL, else XR). 3-product split: Xh*Wh + Xl*Wh + Xh*Wl = 96 MFMA.
// All global accesses coalesced: X float4 loads, lane-ordered B loads (1KB),
// LDS-staged epilogue stores (two full 512B rows per instruction).
__global__ __launch_bounds__(256, 4) void gemm_scatter_kernel(
    const float* __restrict__ X,
    const unsigned short* __restrict__ WBh, const unsigned short* __restrict__ WBlo,
    const float* __restrict__ bl, const float* __restrict__ br,
    float* __restrict__ XL, float* __restrict__ XR,
    const int* __restrict__ edges, int* __restrict__ cnt, int* __restrict__ tbl,
    int fused) {
    __shared__ union SMem {
        struct { unsigned short XH[64 * 64]; unsigned short XLo[64 * 64]; } st;
        float CS[32 * 268];       // epilogue tile, aliases dead staging bufs
    } sm;

    const int t = threadIdx.x;
    int gid;
    if (fused) {
        const int g = blockIdx.x / 3, r = blockIdx.x % 3;
        if (r != 2) {                      // ---- scatter role ----
            const int e = (2 * g + r) * 256 + t;
            if (e < N_EDGES) {
                int s = edges[e];
                int d = edges[N_EDGES + e];
                int slot = atomicAdd(&cnt[d], 1);
                if (slot < CAP) tbl[d * CAP + slot] = s;
            }
            return;
        }
        gid = g;
    } else {
        gid = blockIdx.x;
    }
    const int n0 = gid * 64;

    // stage X -> hi/lo bf16 LDS, chunk-swizzled: elem (row,k) stored at
    // row*64 + ((k>>3 ^ (row&7))<<3) + (k&7). Coalesced global float4 reads.
    #pragma unroll
    for (int p = 0; p < 4; ++p) {
        int f   = p * 256 + t;
        int row = f >> 4, q = f & 15;     // k = 4q..4q+3
        int gn  = n0 + row;
        float4 v = make_float4(0.0f, 0.0f, 0.0f, 0.0f);
        if (gn < N_NODES) v = *(const float4*)(X + (size_t)gn * D_IN + 4 * q);
        ushort4 h, l;
        bf16split(v.x, h.x, l.x); bf16split(v.y, h.y, l.y);
        bf16split(v.z, h.z, l.z); bf16split(v.w, h.w, l.w);
        int off = row * 64 + ((((q >> 1) ^ (row & 7))) << 3) + ((q & 1) << 2);
        *(ushort4*)&sm.st.XH[off]  = h;
        *(ushort4*)&sm.st.XLo[off] = l;
    }
    __syncthreads();

    const int lane = t & 63;
    const int w    = __builtin_amdgcn_readfirstlane(t >> 6);  // wave 0..3
    const float* __restrict__ bp = (w < 2) ? bl : br;
    const int cbase = (w & 1) * 64;       // ch offset within XL/XR
    const int lc    = lane & 15;
    const int lq    = lane >> 4;          // 0..3

    // acc init = bias (C/D col = lane&15; all 4 regs share the col)
    f32x4 acc[4][4];                      // [mt][nt]
    #pragma unroll
    for (int nt = 0; nt < 4; ++nt) {
        float bv = bp[cbase + nt * 16 + lc];
        #pragma unroll
        for (int mt = 0; mt < 4; ++mt)
            acc[mt][nt] = (f32x4){bv, bv, bv, bv};
    }

    #pragma unroll
    for (int kh = 0; kh < 2; ++kh) {
        // B-frags: lane-ordered layout -> contiguous 1KB per load
        bf16x8 Bh[4], Bl[4];
        #pragma unroll
        for (int nt = 0; nt < 4; ++nt) {
            int a = (((w * 4 + nt) * 2 + kh) * 64 + lane) * 8;
            Bh[nt] = *(const bf16x8*)(WBh + a);
            Bl[nt] = *(const bf16x8*)(WBlo + a);
        }
        #pragma unroll
        for (int mt = 0; mt < 4; ++mt) {
            int row = mt * 16 + lc;
            int aoff = row * 64 + ((((kh << 2) + lq) ^ (row & 7)) << 3);
            bf16x8 Ah = *(const bf16x8*)(sm.st.XH + aoff);
            bf16x8 Al = *(const bf16x8*)(sm.st.XLo + aoff);
            #pragma unroll
            for (int nt = 0; nt < 4; ++nt)
                acc[mt][nt] = __builtin_amdgcn_mfma_f32_16x16x32_bf16(Ah, Bh[nt], acc[mt][nt], 0, 0, 0);
            #pragma unroll
            for (int nt = 0; nt < 4; ++nt)
                acc[mt][nt] = __builtin_amdgcn_mfma_f32_16x16x32_bf16(Al, Bh[nt], acc[mt][nt], 0, 0, 0);
            #pragma unroll
            for (int nt = 0; nt < 4; ++nt)
                acc[mt][nt] = __builtin_amdgcn_mfma_f32_16x16x32_bf16(Ah, Bl[nt], acc[mt][nt], 0, 0, 0);
        }
    }

    // LDS-staged epilogue: 2 chunks of 32 rows x 256 unified cols
    // (cols 0-127 = XL, 128-255 = XR; colU = w*64 + nt*16 + lc).
    #pragma unroll
    for (int c = 0; c < 2; ++c) {
        __syncthreads();                  // staging bufs / prev chunk dead
        #pragma unroll
        for (int mt2 = 0; mt2 < 2; ++mt2) {
            int mt = 2 * c + mt2;
            #pragma unroll
            for (int nt = 0; nt < 4; ++nt)
                #pragma unroll
                for (int r = 0; r < 4; ++r)
                    sm.CS[(mt2 * 16 + (lq << 2) + r) * 268 + w * 64 + nt * 16 + lc]
                        = acc[mt][nt][r];
        }
        __syncthreads();
        #pragma unroll
        for (int i = 0; i < 8; ++i) {
            int lr = i * 4 + w;           // 0..31
            int n  = n0 + c * 32 + lr;
            if (n < N_NODES) {
                float4 v4 = *(const float4*)&sm.CS[lr * 268 + 4 * lane];
                float* o = ((lane < 32) ? XL : XR) + (size_t)n * HC + (lane & 31) * 4;
                *(float4*)o = v4;         // lanes 0-31: XL row, 32-63: XR row
            }
        }
    }
}

// ---------------- aggregation: 2 nodes/wave, 2 edges/iter per half ----------
// Half-wave owns one node; lane li = channels 4li..4li+3 of head (lane>>4)&1.
// Round-11 evidence: pk-math was a perf NULL (79us both ways, VALUBusy 61%)
// -> latency-bound on the random 512B gathers, not issue-bound. Fix: 2x the
// memory-level parallelism with TWO independent depth-3 rolling streams
// (even/odd edges, named float4 regs only -> ~52 VGPR, not round-9's array
// blowup). Per iter: consume e0+o0, prefetch edges i+6/i+7. Loop overhead
// per edge halves; the two red16/exp2 chains interleave (2x ILP in the
// serial sections). Prefetches predicated on pf<deg (also fixes latent OOB:
// unwritten tbl slots were read as addresses for pf>=32).
__global__ __launch_bounds__(256) void aggregate_kernel(
    const float* __restrict__ XL, const float* __restrict__ XR,
    const int* __restrict__ cnt, const int* __restrict__ tbl,
    const float* __restrict__ att, const float* __restrict__ bias,
    float* __restrict__ Y, int applyGelu) {
    const int wv   = (blockIdx.x * blockDim.x + threadIdx.x) >> 6;
    const int lane = threadIdx.x & 63;
    const int v    = 2 * wv + (lane >> 5);      // node per 32-lane half
    if (v >= N_NODES) return;
    const int li = lane & 15;
    const int hc = ((lane >> 4) & 1) * 64 + 4 * li;
    const int selbase = lane & 32;              // shfl source base for my half

    const float4 araw = *(const float4*)(att + hc);
    const float4 xr4  = *(const float4*)(XR + (size_t)v * HC + hc);
    const float4 xl4  = *(const float4*)(XL + (size_t)v * HC + hc);

    // 0.6/0.4 * log2(e) * att, packed
    const f32x2 a06_01 = {araw.x * 0.865617024f, araw.y * 0.865617024f};
    const f32x2 a06_23 = {araw.z * 0.865617024f, araw.w * 0.865617024f};
    const f32x2 a04_01 = {araw.x * 0.577078016f, araw.y * 0.577078016f};
    const f32x2 a04_23 = {araw.z * 0.577078016f, araw.w * 0.577078016f};
    const f32x2 xr01 = {xr4.x, xr4.y}, xr23 = {xr4.z, xr4.w};

    // score = sum a06*z + a04*|z|  (== lrelu(z)*att*log2e), packed pipeline
#define SCOREP(C01, C23, OUT)                                                \
    {                                                                        \
        f32x2 q01 = pk_add(C01, xr01), q23 = pk_add(C23, xr23);              \
        f32x2 pa = pk_mul(q01, a06_01);                                      \
        pa = pk_fma(pk_abs(q01), a04_01, pa);                                \
        pa = pk_fma(q23, a06_23, pa);                                        \
        pa = pk_fma(pk_abs(q23), a04_23, pa);                                \
        OUT = pa[0] + pa[1];                                                 \
    }

    // self edge score = shift m0; contributes exp2(0)=1 and xl4
    f32x2 sl01 = {xl4.x, xl4.y}, sl23 = {xl4.z, xl4.w};
    float p;
    SCOREP(sl01, sl23, p)
    const float m0 = red16(p);

    float s = 1.0f;
    f32x2 a01 = sl01, a23 = sl23;

    int deg = cnt[v];
    if (deg > CAP) deg = CAP;
    const int slot = lane & 31;
    const int* __restrict__ tv = tbl + v * CAP;
    int u_l = (slot < deg) ? tv[slot] : 0;

    int dmax = deg;
    { int d2 = __shfl_xor(deg, 32); dmax = d2 > dmax ? d2 : dmax; }

    const float* __restrict__ XLh = XL + hc;

    // two independent depth-3 rolling streams: even edges (e*), odd (o*)
    float4 e0 = make_float4(0,0,0,0), e1 = e0, e2 = e0;
    float4 o0 = e0, o1 = e0, o2 = e0;
#define PFETCH(DST, PF)                                                      \
    if ((PF) < deg) {                                                        \
        int u = ((PF) < 32) ? __shfl(u_l, (PF) + selbase) : tv[(PF)];        \
        DST = *(const float4*)(XLh + (size_t)u * HC);                        \
    }
    PFETCH(e0, 0) PFETCH(o0, 1) PFETCH(e1, 2)
    PFETCH(o1, 3) PFETCH(e2, 4) PFETCH(o2, 5)

    for (int i = 0; i < dmax; i += 2) {
        float4 xa = e0, xb = o0;
        e0 = e1; e1 = e2; o0 = o1; o1 = o2;
        PFETCH(e2, i + 6)
        PFETCH(o2, i + 7)

        f32x2 ca01 = {xa.x, xa.y}, ca23 = {xa.z, xa.w};
        f32x2 cb01 = {xb.x, xb.y}, cb23 = {xb.z, xb.w};
        float pA, pB;
        SCOREP(ca01, ca23, pA)
        SCOREP(cb01, cb23, pB)
        pA = red16(pA);
        pB = red16(pB);
        if (i >= deg)     pA = -1e30f;
        if (i + 1 >= deg) pB = -1e30f;
        float wA = exp2f(pA - m0);
        float wB = exp2f(pB - m0);
        s += wA + wB;
        f32x2 wA2 = {wA, wA}, wB2 = {wB, wB};
        a01 = pk_fma(wA2, ca01, a01);
        a23 = pk_fma(wA2, ca23, a23);
        a01 = pk_fma(wB2, cb01, a01);
        a23 = pk_fma(wB2, cb23, a23);
    }
#undef PFETCH
#undef SCOREP

    float inv = 1.0f / (s + 1e-16f);
    float ax = a01[0] * inv, ay = a01[1] * inv;
    float az = a23[0] * inv, aw = a23[1] * inv;

    // mean over heads (head1 sits at lane^16 within the half)
    ax += __shfl_xor(ax, 16); ay += __shfl_xor(ay, 16);
    az += __shfl_xor(az, 16); aw += __shfl_xor(aw, 16);
    ax *= 0.5f; ay *= 0.5f; az *= 0.5f; aw *= 0.5f;

    if ((lane & 31) < 16) {
        const float4 b4 = *(const float4*)(bias + 4 * li);
        ax += b4.x; ay += b4.y; az += b4.z; aw += b4.w;
        if (applyGelu) { ax = gelu_f(ax); ay = gelu_f(ay); az = gelu_f(az); aw = gelu_f(aw); }
        *(float4*)(Y + (size_t)v * 64 + 4 * li) = make_float4(ax, ay, az, aw);
    }
}

extern "C" void kernel_launch(void* const* d_in, const int* in_sizes, int n_in,
                              void* d_out, int out_size, void* d_ws, size_t ws_size,
                              hipStream_t stream) {
    const float* X     = (const float*)d_in[0];
    const int*   edges = (const int*)d_in[1];
    const float* Wl    = (const float*)d_in[2];
    const float* bl    = (const float*)d_in[3];
    const float* Wr    = (const float*)d_in[4];
    const float* br    = (const float*)d_in[5];
    const float* att   = (const float*)d_in[6];
    const float* bias  = (const float*)d_in[7];

    char* ws = (char*)d_ws;
    float* XLb = (float*)ws;                                          // N*128 f32
    float* XRb = (float*)(ws + (size_t)N_NODES * HC * 4);             // N*128 f32
    float* Yb  = (float*)(ws + (size_t)N_NODES * HC * 8);             // N*64 f32
    int*   cnt = (int*)(ws + (size_t)N_NODES * HC * 8 + (size_t)N_NODES * 64 * 4);
    int*   tbl = cnt + N_NODES;                                       // N*CAP ints
    unsigned short* WBh  = (unsigned short*)(tbl + (size_t)N_NODES * CAP); // 64 KB
    unsigned short* WBlo = WBh + 32768;                                    // 64 KB

    hipMemsetAsync(cnt, 0, N_NODES * sizeof(int), stream);
    wprep_kernel<<<128, 256, 0, stream>>>(Wl, Wr, WBh, WBlo);

    const int agg_grid = ((N_NODES + 1) / 2 * 64 + 255) / 256;        // 2 nodes/wave

    // layer 0: gemm + scatter fused (matrix/mem pipes vs atomic pipe)
    gemm_scatter_kernel<<<FUSED_BLOCKS, 256, 0, stream>>>(
        X, WBh, WBlo, bl, br, XLb, XRb, edges, cnt, tbl, 1);
    aggregate_kernel<<<agg_grid, 256, 0, stream>>>(XLb, XRb, cnt, tbl, att, bias, Yb, 1);
    // layer 1
    gemm_scatter_kernel<<<GEMM_BLOCKS, 256, 0, stream>>>(
        Yb, WBh + 16384, WBlo + 16384, bl + 128, br + 128, XLb, XRb, edges, cnt, tbl, 0);
    aggregate_kernel<<<agg_grid, 256, 0, stream>>>(XLb, XRb, cnt, tbl, att + 128, bias + 64,
                                                   (float*)d_out, 0);
}

// Round 13
// 314.663 us; speedup vs baseline: 1.0529x; 1.0529x over previous
//
#include <hip/hip_runtime.h>
#include <math.h>

#define N_NODES 100000
#define N_EDGES 800000
#define D_IN    64
#define HC      128   // H*C
#define CAP     48    // max in-degree slots (Poisson(8): P(>48) ~ 0)

#define GEMM_BLOCKS 1563                 // ceil(100000/64)
#define FUSED_BLOCKS (3 * GEMM_BLOCKS)   // bid%3==2 -> gemm, else scatter

typedef short bf16x8 __attribute__((ext_vector_type(8)));   // 8 bf16 = 4 VGPR
typedef float f32x4  __attribute__((ext_vector_type(4)));
typedef float f32x2  __attribute__((ext_vector_type(2)));

// ---- CDNA packed fp32 (VOP3P, full rate; gfx950 has add/mul/fma ONLY) ----
__device__ __forceinline__ f32x2 pk_add(f32x2 a, f32x2 b) {
    f32x2 d; asm("v_pk_add_f32 %0, %1, %2" : "=v"(d) : "v"(a), "v"(b)); return d;
}
__device__ __forceinline__ f32x2 pk_mul(f32x2 a, f32x2 b) {
    f32x2 d; asm("v_pk_mul_f32 %0, %1, %2" : "=v"(d) : "v"(a), "v"(b)); return d;
}
__device__ __forceinline__ f32x2 pk_fma(f32x2 a, f32x2 b, f32x2 c) {
    f32x2 d; asm("v_pk_fma_f32 %0, %1, %2, %3" : "=v"(d) : "v"(a), "v"(b), "v"(c)); return d;
}
// |x| per half: two full-rate v_and_b32 (no packed max on gfx950)
__device__ __forceinline__ f32x2 pk_abs(f32x2 a) {
    f32x2 d; d[0] = fabsf(a[0]); d[1] = fabsf(a[1]); return d;
}

// tanh-approx gelu (jax.nn.gelu default approximate=True)
__device__ __forceinline__ float gelu_f(float x) {
    float x3 = x * x * x;
    float y  = 0.7978845608028654f * (x + 0.044715f * x3);
    float t = 1.0f - 2.0f / (__expf(2.0f * y) + 1.0f);
    return 0.5f * x * (1.0f + t);
}

// sum across a 16-lane row via DPP row_ror (pure VALU, no ds_swizzle)
__device__ __forceinline__ float red16(float x) {
    x += __int_as_float(__builtin_amdgcn_mov_dpp(__float_as_int(x), 0x128, 0xF, 0xF, true)); // ror:8
    x += __int_as_float(__builtin_amdgcn_mov_dpp(__float_as_int(x), 0x124, 0xF, 0xF, true)); // ror:4
    x += __int_as_float(__builtin_amdgcn_mov_dpp(__float_as_int(x), 0x122, 0xF, 0xF, true)); // ror:2
    x += __int_as_float(__builtin_amdgcn_mov_dpp(__float_as_int(x), 0x121, 0xF, 0xF, true)); // ror:1
    return x;
}

// split fp32 -> bf16 hi (rne) + bf16 lo (rne of residual); x = h + l + O(2^-18 x)
__device__ __forceinline__ void bf16split(float x, unsigned short& h, unsigned short& l) {
    unsigned b  = __float_as_uint(x);
    unsigned hb = (b + 0x7FFFu + ((b >> 16) & 1u)) & 0xFFFF0000u;
    h = (unsigned short)(hb >> 16);
    float lo = x - __uint_as_float(hb);
    unsigned c = __float_as_uint(lo);
    l = (unsigned short)((c + 0x7FFFu + ((c >> 16) & 1u)) >> 16);
}

// ---------------- W prep: lane-ordered bf16 hi/lo (+ cnt zeroing) -----------
// WB3[layer][w][nt][kh][lane][8] = exactly the consumption order of wave w's
// B-fragments -> every B-frag load in the gemm is 64 lanes x contiguous 16B
// = one coalesced 1KB request. Also zeroes cnt (grid-stride) -> drops the
// separate hipMemsetAsync launch.
__global__ __launch_bounds__(256) void wprep_kernel(
    const float* __restrict__ Wl, const float* __restrict__ Wr,
    unsigned short* __restrict__ WBh, unsigned short* __restrict__ WBlo,
    int* __restrict__ cnt) {
    int g = blockIdx.x * 256 + threadIdx.x;       // 0..32767
    for (int z = g; z < N_NODES; z += 32768) cnt[z] = 0;
    int layer = g >> 14;
    int rem   = g & 16383;        // (((w*4+nt)*2+kh)*64 + lane)*8 + j
    int j    = rem & 7;
    int idx  = rem >> 3;
    int lane = idx & 63;
    int kh   = (idx >> 6) & 1;
    int nt   = (idx >> 7) & 3;
    int w    = (idx >> 9) & 3;
    int col  = w * 64 + nt * 16 + (lane & 15);    // 0..255 (128+ = Wr)
    int k    = kh * 32 + (lane >> 4) * 8 + j;
    const float* W = (col < 128) ? Wl : Wr;
    float x = W[layer * 8192 + k * HC + (col & 127)];
    unsigned short h, l;
    bf16split(x, h, l);
    WBh[g] = h; WBlo[g] = l;
}

// ---------------- fused split-bf16 MFMA GEMM (+ scatter role) ---------------
// [N,64]@[64,256]: block = 64 nodes x 256 ch, 4 waves; wave w = 64 ch
// (w<2 -> XL, else XR). 3-product split: Xh*Wh + Xl*Wh + Xh*Wl = 96 MFMA.
// All global accesses coalesced: X float4 loads, lane-ordered B loads (1KB),
// LDS-staged epilogue stores (two full 512B rows per instruction).
__global__ __launch_bounds__(256, 4) void gemm_scatter_kernel(
    const float* __restrict__ X,
    const unsigned short* __restrict__ WBh, const unsigned short* __restrict__ WBlo,
    const float* __restrict__ bl, const float* __restrict__ br,
    float* __restrict__ XL, float* __restrict__ XR,
    const int* __restrict__ edges, int* __restrict__ cnt, int* __restrict__ tbl,
    int fused) {
    __shared__ union SMem {
        struct { unsigned short XH[64 * 64]; unsigned short XLo[64 * 64]; } st;
        float CS[32 * 268];       // epilogue tile, aliases dead staging bufs
    } sm;

    const int t = threadIdx.x;
    int gid;
    if (fused) {
        const int g = blockIdx.x / 3, r = blockIdx.x % 3;
        if (r != 2) {                      // ---- scatter role ----
            const int e = (2 * g + r) * 256 + t;
            if (e < N_EDGES) {
                int s = edges[e];
                int d = edges[N_EDGES + e];
                int slot = atomicAdd(&cnt[d], 1);
                if (slot < CAP) tbl[d * CAP + slot] = s;
            }
            return;
        }
        gid = g;
    } else {
        gid = blockIdx.x;
    }
    const int n0 = gid * 64;

    // stage X -> hi/lo bf16 LDS, chunk-swizzled: elem (row,k) stored at
    // row*64 + ((k>>3 ^ (row&7))<<3) + (k&7). Coalesced global float4 reads.
    #pragma unroll
    for (int p = 0; p < 4; ++p) {
        int f   = p * 256 + t;
        int row = f >> 4, q = f & 15;     // k = 4q..4q+3
        int gn  = n0 + row;
        float4 v = make_float4(0.0f, 0.0f, 0.0f, 0.0f);
        if (gn < N_NODES) v = *(const float4*)(X + (size_t)gn * D_IN + 4 * q);
        ushort4 h, l;
        bf16split(v.x, h.x, l.x); bf16split(v.y, h.y, l.y);
        bf16split(v.z, h.z, l.z); bf16split(v.w, h.w, l.w);
        int off = row * 64 + ((((q >> 1) ^ (row & 7))) << 3) + ((q & 1) << 2);
        *(ushort4*)&sm.st.XH[off]  = h;
        *(ushort4*)&sm.st.XLo[off] = l;
    }
    __syncthreads();

    const int lane = t & 63;
    const int w    = __builtin_amdgcn_readfirstlane(t >> 6);  // wave 0..3
    const float* __restrict__ bp = (w < 2) ? bl : br;
    const int cbase = (w & 1) * 64;       // ch offset within XL/XR
    const int lc    = lane & 15;
    const int lq    = lane >> 4;          // 0..3

    // acc init = bias (C/D col = lane&15; all 4 regs share the col)
    f32x4 acc[4][4];                      // [mt][nt]
    #pragma unroll
    for (int nt = 0; nt < 4; ++nt) {
        float bv = bp[cbase + nt * 16 + lc];
        #pragma unroll
        for (int mt = 0; mt < 4; ++mt)
            acc[mt][nt] = (f32x4){bv, bv, bv, bv};
    }

    #pragma unroll
    for (int kh = 0; kh < 2; ++kh) {
        // B-frags: lane-ordered layout -> contiguous 1KB per load
        bf16x8 Bh[4], Bl[4];
        #pragma unroll
        for (int nt = 0; nt < 4; ++nt) {
            int a = (((w * 4 + nt) * 2 + kh) * 64 + lane) * 8;
            Bh[nt] = *(const bf16x8*)(WBh + a);
            Bl[nt] = *(const bf16x8*)(WBlo + a);
        }
        #pragma unroll
        for (int mt = 0; mt < 4; ++mt) {
            int row = mt * 16 + lc;
            int aoff = row * 64 + ((((kh << 2) + lq) ^ (row & 7)) << 3);
            bf16x8 Ah = *(const bf16x8*)(sm.st.XH + aoff);
            bf16x8 Al = *(const bf16x8*)(sm.st.XLo + aoff);
            #pragma unroll
            for (int nt = 0; nt < 4; ++nt)
                acc[mt][nt] = __builtin_amdgcn_mfma_f32_16x16x32_bf16(Ah, Bh[nt], acc[mt][nt], 0, 0, 0);
            #pragma unroll
            for (int nt = 0; nt < 4; ++nt)
                acc[mt][nt] = __builtin_amdgcn_mfma_f32_16x16x32_bf16(Al, Bh[nt], acc[mt][nt], 0, 0, 0);
            #pragma unroll
            for (int nt = 0; nt < 4; ++nt)
                acc[mt][nt] = __builtin_amdgcn_mfma_f32_16x16x32_bf16(Ah, Bl[nt], acc[mt][nt], 0, 0, 0);
        }
    }

    // LDS-staged epilogue: 2 chunks of 32 rows x 256 unified cols
    // (cols 0-127 = XL, 128-255 = XR; colU = w*64 + nt*16 + lc).
    #pragma unroll
    for (int c = 0; c < 2; ++c) {
        __syncthreads();                  // staging bufs / prev chunk dead
        #pragma unroll
        for (int mt2 = 0; mt2 < 2; ++mt2) {
            int mt = 2 * c + mt2;
            #pragma unroll
            for (int nt = 0; nt < 4; ++nt)
                #pragma unroll
                for (int r = 0; r < 4; ++r)
                    sm.CS[(mt2 * 16 + (lq << 2) + r) * 268 + w * 64 + nt * 16 + lc]
                        = acc[mt][nt][r];
        }
        __syncthreads();
        #pragma unroll
        for (int i = 0; i < 8; ++i) {
            int lr = i * 4 + w;           // 0..31
            int n  = n0 + c * 32 + lr;
            if (n < N_NODES) {
                float4 v4 = *(const float4*)&sm.CS[lr * 268 + 4 * lane];
                float* o = ((lane < 32) ? XL : XR) + (size_t)n * HC + (lane & 31) * 4;
                *(float4*)o = v4;         // lanes 0-31: XL row, 32-63: XR row
            }
        }
    }
}

// ---------------- aggregation: 2 NODES per wave (measured-best structure) ---
// Half-wave owns one node; lane li = channels 4li..4li+3 of head (lane>>4)&1.
// Rolling depth-3 window, single stream. 12-round A/B record: static pipeline
// (r9) -56%, pk-math (r11) null, dual-stream MLP (r12) -9% -> this structure
// is at the random-512B-gather ceiling (3.45 TB/s, 55% of achievable on
// cacheline-granular access). Packed fp32 kept (free, slightly fewer instr).
__global__ __launch_bounds__(256) void aggregate_kernel(
    const float* __restrict__ XL, const float* __restrict__ XR,
    const int* __restrict__ cnt, const int* __restrict__ tbl,
    const float* __restrict__ att, const float* __restrict__ bias,
    float* __restrict__ Y, int applyGelu) {
    const int wv   = (blockIdx.x * blockDim.x + threadIdx.x) >> 6;
    const int lane = threadIdx.x & 63;
    const int v    = 2 * wv + (lane >> 5);      // node per 32-lane half
    if (v >= N_NODES) return;
    const int li = lane & 15;
    const int hc = ((lane >> 4) & 1) * 64 + 4 * li;
    const int selbase = lane & 32;              // shfl source base for my half

    const float4 araw = *(const float4*)(att + hc);
    const float4 xr4  = *(const float4*)(XR + (size_t)v * HC + hc);
    const float4 xl4  = *(const float4*)(XL + (size_t)v * HC + hc);

    // 0.6/0.4 * log2(e) * att, packed
    const f32x2 a06_01 = {araw.x * 0.865617024f, araw.y * 0.865617024f};
    const f32x2 a06_23 = {araw.z * 0.865617024f, araw.w * 0.865617024f};
    const f32x2 a04_01 = {araw.x * 0.577078016f, araw.y * 0.577078016f};
    const f32x2 a04_23 = {araw.z * 0.577078016f, araw.w * 0.577078016f};
    const f32x2 xr01 = {xr4.x, xr4.y}, xr23 = {xr4.z, xr4.w};

    // score = sum a06*z + a04*|z|  (== lrelu(z)*att*log2e), packed pipeline
#define SCOREP(C01, C23, OUT)                                                \
    {                                                                        \
        f32x2 q01 = pk_add(C01, xr01), q23 = pk_add(C23, xr23);              \
        f32x2 pa = pk_mul(q01, a06_01);                                      \
        pa = pk_fma(pk_abs(q01), a04_01, pa);                                \
        pa = pk_fma(q23, a06_23, pa);                                        \
        pa = pk_fma(pk_abs(q23), a04_23, pa);                                \
        OUT = pa[0] + pa[1];                                                 \
    }

    // self edge score = shift m0; contributes exp2(0)=1 and xl4
    f32x2 sl01 = {xl4.x, xl4.y}, sl23 = {xl4.z, xl4.w};
    float p;
    SCOREP(sl01, sl23, p)
    const float m0 = red16(p);

    float s = 1.0f;
    f32x2 a01 = sl01, a23 = sl23;

    int deg = cnt[v];
    if (deg > CAP) deg = CAP;
    const int slot = lane & 31;
    const int* __restrict__ tv = tbl + v * CAP;
    int u_l = (slot < deg) ? tv[slot] : 0;

    int dmax = deg;
    { int d2 = __shfl_xor(deg, 32); dmax = d2 > dmax ? d2 : dmax; }

    const float* __restrict__ XLh = XL + hc;

    // depth-3 rolling prefetch (per half)
    float4 x0 = make_float4(0,0,0,0), x1 = x0, x2 = x0;
    if (dmax > 0) { int u = __shfl(u_l, 0 + selbase); x0 = *(const float4*)(XLh + (size_t)u * HC); }
    if (dmax > 1) { int u = __shfl(u_l, 1 + selbase); x1 = *(const float4*)(XLh + (size_t)u * HC); }
    if (dmax > 2) { int u = __shfl(u_l, 2 + selbase); x2 = *(const float4*)(XLh + (size_t)u * HC); }

    for (int i = 0; i < dmax; ++i) {
        float4 xc = x0; x0 = x1; x1 = x2;
        int pf = i + 3;
        if (pf < dmax) {
            int u = (pf < 32) ? __shfl(u_l, pf + selbase) : tv[pf];
            x2 = *(const float4*)(XLh + (size_t)u * HC);
        }
        f32x2 c01 = {xc.x, xc.y}, c23 = {xc.z, xc.w};
        SCOREP(c01, c23, p)
        p = red16(p);
        if (i >= deg) p = -1e30f;               // other half longer -> mask
        float w = exp2f(p - m0);
        s += w;
        f32x2 w2 = {w, w};
        a01 = pk_fma(w2, c01, a01);
        a23 = pk_fma(w2, c23, a23);
    }
#undef SCOREP

    float inv = 1.0f / (s + 1e-16f);
    float ax = a01[0] * inv, ay = a01[1] * inv;
    float az = a23[0] * inv, aw = a23[1] * inv;

    // mean over heads (head1 sits at lane^16 within the half)
    ax += __shfl_xor(ax, 16); ay += __shfl_xor(ay, 16);
    az += __shfl_xor(az, 16); aw += __shfl_xor(aw, 16);
    ax *= 0.5f; ay *= 0.5f; az *= 0.5f; aw *= 0.5f;

    if ((lane & 31) < 16) {
        const float4 b4 = *(const float4*)(bias + 4 * li);
        ax += b4.x; ay += b4.y; az += b4.z; aw += b4.w;
        if (applyGelu) { ax = gelu_f(ax); ay = gelu_f(ay); az = gelu_f(az); aw = gelu_f(aw); }
        *(float4*)(Y + (size_t)v * 64 + 4 * li) = make_float4(ax, ay, az, aw);
    }
}

extern "C" void kernel_launch(void* const* d_in, const int* in_sizes, int n_in,
                              void* d_out, int out_size, void* d_ws, size_t ws_size,
                              hipStream_t stream) {
    const float* X     = (const float*)d_in[0];
    const int*   edges = (const int*)d_in[1];
    const float* Wl    = (const float*)d_in[2];
    const float* bl    = (const float*)d_in[3];
    const float* Wr    = (const float*)d_in[4];
    const float* br    = (const float*)d_in[5];
    const float* att   = (const float*)d_in[6];
    const float* bias  = (const float*)d_in[7];

    char* ws = (char*)d_ws;
    float* XLb = (float*)ws;                                          // N*128 f32
    float* XRb = (float*)(ws + (size_t)N_NODES * HC * 4);             // N*128 f32
    float* Yb  = (float*)(ws + (size_t)N_NODES * HC * 8);             // N*64 f32
    int*   cnt = (int*)(ws + (size_t)N_NODES * HC * 8 + (size_t)N_NODES * 64 * 4);
    int*   tbl = cnt + N_NODES;                                       // N*CAP ints
    unsigned short* WBh  = (unsigned short*)(tbl + (size_t)N_NODES * CAP); // 64 KB
    unsigned short* WBlo = WBh + 32768;                                    // 64 KB

    // wprep also zeroes cnt (grid-stride) -> no separate memset launch
    wprep_kernel<<<128, 256, 0, stream>>>(Wl, Wr, WBh, WBlo, cnt);

    const int agg_grid = ((N_NODES + 1) / 2 * 64 + 255) / 256;        // 2 nodes/wave

    // layer 0: gemm + scatter fused (matrix/mem pipes vs atomic pipe)
    gemm_scatter_kernel<<<FUSED_BLOCKS, 256, 0, stream>>>(
        X, WBh, WBlo, bl, br, XLb, XRb, edges, cnt, tbl, 1);
    aggregate_kernel<<<agg_grid, 256, 0, stream>>>(XLb, XRb, cnt, tbl, att, bias, Yb, 1);
    // layer 1
    gemm_scatter_kernel<<<GEMM_BLOCKS, 256, 0, stream>>>(
        Yb, WBh + 16384, WBlo + 16384, bl + 128, br + 128, XLb, XRb, edges, cnt, tbl, 0);
    aggregate_kernel<<<agg_grid, 256, 0, stream>>>(XLb, XRb, cnt, tbl, att + 128, bias + 64,
                                                   (float*)d_out, 0);
}

// Round 14
// 269.311 us; speedup vs baseline: 1.2302x; 1.1684x over previous
//
#include <hip/hip_runtime.h>
#include <hip/hip_fp16.h>
#include <math.h>

#define N_NODES 100000
#define N_EDGES 800000
#define D_IN    64
#define HC      128   // H*C
#define CAP     48    // max in-degree slots (Poisson(8): P(>48) ~ 0)

#define GEMM_BLOCKS 1563                 // ceil(100000/64)
#define FUSED_BLOCKS (3 * GEMM_BLOCKS)   // bid%3==2 -> gemm, else scatter

typedef short bf16x8 __attribute__((ext_vector_type(8)));   // 8 bf16 = 4 VGPR
typedef float f32x4  __attribute__((ext_vector_type(4)));
typedef float f32x2  __attribute__((ext_vector_type(2)));

// ---- CDNA packed fp32 (VOP3P, full rate; gfx950 has add/mul/fma ONLY) ----
__device__ __forceinline__ f32x2 pk_add(f32x2 a, f32x2 b) {
    f32x2 d; asm("v_pk_add_f32 %0, %1, %2" : "=v"(d) : "v"(a), "v"(b)); return d;
}
__device__ __forceinline__ f32x2 pk_mul(f32x2 a, f32x2 b) {
    f32x2 d; asm("v_pk_mul_f32 %0, %1, %2" : "=v"(d) : "v"(a), "v"(b)); return d;
}
__device__ __forceinline__ f32x2 pk_fma(f32x2 a, f32x2 b, f32x2 c) {
    f32x2 d; asm("v_pk_fma_f32 %0, %1, %2, %3" : "=v"(d) : "v"(a), "v"(b), "v"(c)); return d;
}
// |x| per half: two full-rate v_and_b32 (no packed max on gfx950)
__device__ __forceinline__ f32x2 pk_abs(f32x2 a) {
    f32x2 d; d[0] = fabsf(a[0]); d[1] = fabsf(a[1]); return d;
}

// unpack 4 packed fp16 (uint2) -> float4
__device__ __forceinline__ float4 up4(uint2 p) {
    __half2 h0 = *(__half2*)&p.x, h1 = *(__half2*)&p.y;
    float2 f0 = __half22float2(h0), f1 = __half22float2(h1);
    return make_float4(f0.x, f0.y, f1.x, f1.y);
}

// tanh-approx gelu (jax.nn.gelu default approximate=True)
__device__ __forceinline__ float gelu_f(float x) {
    float x3 = x * x * x;
    float y  = 0.7978845608028654f * (x + 0.044715f * x3);
    float t = 1.0f - 2.0f / (__expf(2.0f * y) + 1.0f);
    return 0.5f * x * (1.0f + t);
}

// sum across a 16-lane row via DPP row_ror (pure VALU, no ds_swizzle)
__device__ __forceinline__ float red16(float x) {
    x += __int_as_float(__builtin_amdgcn_mov_dpp(__float_as_int(x), 0x128, 0xF, 0xF, true)); // ror:8
    x += __int_as_float(__builtin_amdgcn_mov_dpp(__float_as_int(x), 0x124, 0xF, 0xF, true)); // ror:4
    x += __int_as_float(__builtin_amdgcn_mov_dpp(__float_as_int(x), 0x122, 0xF, 0xF, true)); // ror:2
    x += __int_as_float(__builtin_amdgcn_mov_dpp(__float_as_int(x), 0x121, 0xF, 0xF, true)); // ror:1
    return x;
}

// split fp32 -> bf16 hi (rne) + bf16 lo (rne of residual); x = h + l + O(2^-18 x)
__device__ __forceinline__ void bf16split(float x, unsigned short& h, unsigned short& l) {
    unsigned b  = __float_as_uint(x);
    unsigned hb = (b + 0x7FFFu + ((b >> 16) & 1u)) & 0xFFFF0000u;
    h = (unsigned short)(hb >> 16);
    float lo = x - __uint_as_float(hb);
    unsigned c = __float_as_uint(lo);
    l = (unsigned short)((c + 0x7FFFu + ((c >> 16) & 1u)) >> 16);
}

// ---------------- W prep: lane-ordered bf16 hi/lo (+ cnt zeroing) -----------
// WB3[layer][w][nt][kh][lane][8] = exactly the consumption order of wave w's
// B-fragments -> every B-frag load in the gemm is 64 lanes x contiguous 16B
// = one coalesced 1KB request. Also zeroes cnt (grid-stride) -> drops the
// separate hipMemsetAsync launch.
__global__ __launch_bounds__(256) void wprep_kernel(
    const float* __restrict__ Wl, const float* __restrict__ Wr,
    unsigned short* __restrict__ WBh, unsigned short* __restrict__ WBlo,
    int* __restrict__ cnt) {
    int g = blockIdx.x * 256 + threadIdx.x;       // 0..32767
    for (int z = g; z < N_NODES; z += 32768) cnt[z] = 0;
    int layer = g >> 14;
    int rem   = g & 16383;        // (((w*4+nt)*2+kh)*64 + lane)*8 + j
    int j    = rem & 7;
    int idx  = rem >> 3;
    int lane = idx & 63;
    int kh   = (idx >> 6) & 1;
    int nt   = (idx >> 7) & 3;
    int w    = (idx >> 9) & 3;
    int col  = w * 64 + nt * 16 + (lane & 15);    // 0..255 (128+ = Wr)
    int k    = kh * 32 + (lane >> 4) * 8 + j;
    const float* W = (col < 128) ? Wl : Wr;
    float x = W[layer * 8192 + k * HC + (col & 127)];
    unsigned short h, l;
    bf16split(x, h, l);
    WBh[g] = h; WBlo[g] = l;
}

// ---------------- fused split-bf16 MFMA GEMM (+ scatter role) ---------------
// [N,64]@[64,256]: block = 64 nodes x 256 ch, 4 waves; wave w = 64 ch
// (w<2 -> XL, else XR). 3-product split: Xh*Wh + Xl*Wh + Xh*Wl = 96 MFMA.
// XL/XR now stored FP16 (round-14): halves agg gather bytes (the byte term
// of its roofline) and the epilogue write traffic. Epilogue still stores two
// full (256B) rows per instruction.
__global__ __launch_bounds__(256, 4) void gemm_scatter_kernel(
    const float* __restrict__ X,
    const unsigned short* __restrict__ WBh, const unsigned short* __restrict__ WBlo,
    const float* __restrict__ bl, const float* __restrict__ br,
    __half* __restrict__ XL, __half* __restrict__ XR,
    const int* __restrict__ edges, int* __restrict__ cnt, int* __restrict__ tbl,
    int fused) {
    __shared__ union SMem {
        struct { unsigned short XH[64 * 64]; unsigned short XLo[64 * 64]; } st;
        float CS[32 * 268];       // epilogue tile, aliases dead staging bufs
    } sm;

    const int t = threadIdx.x;
    int gid;
    if (fused) {
        const int g = blockIdx.x / 3, r = blockIdx.x % 3;
        if (r != 2) {                      // ---- scatter role ----
            const int e = (2 * g + r) * 256 + t;
            if (e < N_EDGES) {
                int s = edges[e];
                int d = edges[N_EDGES + e];
                int slot = atomicAdd(&cnt[d], 1);
                if (slot < CAP) tbl[d * CAP + slot] = s;
            }
            return;
        }
        gid = g;
    } else {
        gid = blockIdx.x;
    }
    const int n0 = gid * 64;

    // stage X -> hi/lo bf16 LDS, chunk-swizzled: elem (row,k) stored at
    // row*64 + ((k>>3 ^ (row&7))<<3) + (k&7). Coalesced global float4 reads.
    #pragma unroll
    for (int p = 0; p < 4; ++p) {
        int f   = p * 256 + t;
        int row = f >> 4, q = f & 15;     // k = 4q..4q+3
        int gn  = n0 + row;
        float4 v = make_float4(0.0f, 0.0f, 0.0f, 0.0f);
        if (gn < N_NODES) v = *(const float4*)(X + (size_t)gn * D_IN + 4 * q);
        ushort4 h, l;
        bf16split(v.x, h.x, l.x); bf16split(v.y, h.y, l.y);
        bf16split(v.z, h.z, l.z); bf16split(v.w, h.w, l.w);
        int off = row * 64 + ((((q >> 1) ^ (row & 7))) << 3) + ((q & 1) << 2);
        *(ushort4*)&sm.st.XH[off]  = h;
        *(ushort4*)&sm.st.XLo[off] = l;
    }
    __syncthreads();

    const int lane = t & 63;
    const int w    = __builtin_amdgcn_readfirstlane(t >> 6);  // wave 0..3
    const float* __restrict__ bp = (w < 2) ? bl : br;
    const int cbase = (w & 1) * 64;       // ch offset within XL/XR
    const int lc    = lane & 15;
    const int lq    = lane >> 4;          // 0..3

    // acc init = bias (C/D col = lane&15; all 4 regs share the col)
    f32x4 acc[4][4];                      // [mt][nt]
    #pragma unroll
    for (int nt = 0; nt < 4; ++nt) {
        float bv = bp[cbase + nt * 16 + lc];
        #pragma unroll
        for (int mt = 0; mt < 4; ++mt)
            acc[mt][nt] = (f32x4){bv, bv, bv, bv};
    }

    #pragma unroll
    for (int kh = 0; kh < 2; ++kh) {
        // B-frags: lane-ordered layout -> contiguous 1KB per load
        bf16x8 Bh[4], Bl[4];
        #pragma unroll
        for (int nt = 0; nt < 4; ++nt) {
            int a = (((w * 4 + nt) * 2 + kh) * 64 + lane) * 8;
            Bh[nt] = *(const bf16x8*)(WBh + a);
            Bl[nt] = *(const bf16x8*)(WBlo + a);
        }
        #pragma unroll
        for (int mt = 0; mt < 4; ++mt) {
            int row = mt * 16 + lc;
            int aoff = row * 64 + ((((kh << 2) + lq) ^ (row & 7)) << 3);
            bf16x8 Ah = *(const bf16x8*)(sm.st.XH + aoff);
            bf16x8 Al = *(const bf16x8*)(sm.st.XLo + aoff);
            #pragma unroll
            for (int nt = 0; nt < 4; ++nt)
                acc[mt][nt] = __builtin_amdgcn_mfma_f32_16x16x32_bf16(Ah, Bh[nt], acc[mt][nt], 0, 0, 0);
            #pragma unroll
            for (int nt = 0; nt < 4; ++nt)
                acc[mt][nt] = __builtin_amdgcn_mfma_f32_16x16x32_bf16(Al, Bh[nt], acc[mt][nt], 0, 0, 0);
            #pragma unroll
            for (int nt = 0; nt < 4; ++nt)
                acc[mt][nt] = __builtin_amdgcn_mfma_f32_16x16x32_bf16(Ah, Bl[nt], acc[mt][nt], 0, 0, 0);
        }
    }

    // LDS-staged epilogue: 2 chunks of 32 rows x 256 unified cols
    // (cols 0-127 = XL, 128-255 = XR; colU = w*64 + nt*16 + lc). fp16 pack at
    // readback: lane covers 4 ch = 8B; 32 lanes = full 256B row.
    #pragma unroll
    for (int c = 0; c < 2; ++c) {
        __syncthreads();                  // staging bufs / prev chunk dead
        #pragma unroll
        for (int mt2 = 0; mt2 < 2; ++mt2) {
            int mt = 2 * c + mt2;
            #pragma unroll
            for (int nt = 0; nt < 4; ++nt)
                #pragma unroll
                for (int r = 0; r < 4; ++r)
                    sm.CS[(mt2 * 16 + (lq << 2) + r) * 268 + w * 64 + nt * 16 + lc]
                        = acc[mt][nt][r];
        }
        __syncthreads();
        #pragma unroll
        for (int i = 0; i < 8; ++i) {
            int lr = i * 4 + w;           // 0..31
            int n  = n0 + c * 32 + lr;
            if (n < N_NODES) {
                float4 v4 = *(const float4*)&sm.CS[lr * 268 + 4 * lane];
                __half2 h01 = __float22half2_rn(make_float2(v4.x, v4.y));
                __half2 h23 = __float22half2_rn(make_float2(v4.z, v4.w));
                uint2 pk;
                pk.x = *(unsigned*)&h01; pk.y = *(unsigned*)&h23;
                __half* o = ((lane < 32) ? XL : XR) + (size_t)n * HC + (lane & 31) * 4;
                *(uint2*)o = pk;          // lanes 0-31: XL row, 32-63: XR row
            }
        }
    }
}

// ---------------- aggregation: 2 NODES per wave, fp16 gathers ---------------
// Half-wave owns one node; lane li = channels 4li..4li+3 of head (lane>>4)&1.
// Rolling depth-3 window (measured-best structure, r8-r13 A/B ledger).
// Round-14: XL/XR are fp16 -> gather = 8B/lane uint2 (256B/row, HALF the
// bytes of r13). Convert at consume (cvt is free here: r11 proved instr count
// is not the limit). Prefetch regs halve (uint2 vs float4).
__global__ __launch_bounds__(256) void aggregate_kernel(
    const __half* __restrict__ XL, const __half* __restrict__ XR,
    const int* __restrict__ cnt, const int* __restrict__ tbl,
    const float* __restrict__ att, const float* __restrict__ bias,
    float* __restrict__ Y, int applyGelu) {
    const int wv   = (blockIdx.x * blockDim.x + threadIdx.x) >> 6;
    const int lane = threadIdx.x & 63;
    const int v    = 2 * wv + (lane >> 5);      // node per 32-lane half
    if (v >= N_NODES) return;
    const int li = lane & 15;
    const int hc = ((lane >> 4) & 1) * 64 + 4 * li;
    const int selbase = lane & 32;              // shfl source base for my half

    const float4 araw = *(const float4*)(att + hc);
    const float4 xr4  = up4(*(const uint2*)(XR + (size_t)v * HC + hc));
    const float4 xl4  = up4(*(const uint2*)(XL + (size_t)v * HC + hc));

    // 0.6/0.4 * log2(e) * att, packed
    const f32x2 a06_01 = {araw.x * 0.865617024f, araw.y * 0.865617024f};
    const f32x2 a06_23 = {araw.z * 0.865617024f, araw.w * 0.865617024f};
    const f32x2 a04_01 = {araw.x * 0.577078016f, araw.y * 0.577078016f};
    const f32x2 a04_23 = {araw.z * 0.577078016f, araw.w * 0.577078016f};
    const f32x2 xr01 = {xr4.x, xr4.y}, xr23 = {xr4.z, xr4.w};

    // score = sum a06*z + a04*|z|  (== lrelu(z)*att*log2e), packed pipeline
#define SCOREP(C01, C23, OUT)                                                \
    {                                                                        \
        f32x2 q01 = pk_add(C01, xr01), q23 = pk_add(C23, xr23);              \
        f32x2 pa = pk_mul(q01, a06_01);                                      \
        pa = pk_fma(pk_abs(q01), a04_01, pa);                                \
        pa = pk_fma(q23, a06_23, pa);                                        \
        pa = pk_fma(pk_abs(q23), a04_23, pa);                                \
        OUT = pa[0] + pa[1];                                                 \
    }

    // self edge score = shift m0; contributes exp2(0)=1 and xl4
    f32x2 sl01 = {xl4.x, xl4.y}, sl23 = {xl4.z, xl4.w};
    float p;
    SCOREP(sl01, sl23, p)
    const float m0 = red16(p);

    float s = 1.0f;
    f32x2 a01 = sl01, a23 = sl23;

    int deg = cnt[v];
    if (deg > CAP) deg = CAP;
    const int slot = lane & 31;
    const int* __restrict__ tv = tbl + v * CAP;
    int u_l = (slot < deg) ? tv[slot] : 0;

    int dmax = deg;
    { int d2 = __shfl_xor(deg, 32); dmax = d2 > dmax ? d2 : dmax; }

    const __half* __restrict__ XLh = XL + hc;

    // depth-3 rolling prefetch (per half), 8B uint2 per gather
    uint2 x0 = make_uint2(0, 0), x1 = x0, x2 = x0;
    if (dmax > 0) { int u = __shfl(u_l, 0 + selbase); x0 = *(const uint2*)(XLh + (size_t)u * HC); }
    if (dmax > 1) { int u = __shfl(u_l, 1 + selbase); x1 = *(const uint2*)(XLh + (size_t)u * HC); }
    if (dmax > 2) { int u = __shfl(u_l, 2 + selbase); x2 = *(const uint2*)(XLh + (size_t)u * HC); }

    for (int i = 0; i < dmax; ++i) {
        uint2 xp = x0; x0 = x1; x1 = x2;
        int pf = i + 3;
        if (pf < dmax) {
            int u = (pf < 32) ? __shfl(u_l, pf + selbase) : tv[pf];
            x2 = *(const uint2*)(XLh + (size_t)u * HC);
        }
        float4 xc = up4(xp);
        f32x2 c01 = {xc.x, xc.y}, c23 = {xc.z, xc.w};
        SCOREP(c01, c23, p)
        p = red16(p);
        if (i >= deg) p = -1e30f;               // other half longer -> mask
        float w = exp2f(p - m0);
        s += w;
        f32x2 w2 = {w, w};
        a01 = pk_fma(w2, c01, a01);
        a23 = pk_fma(w2, c23, a23);
    }
#undef SCOREP

    float inv = 1.0f / (s + 1e-16f);
    float ax = a01[0] * inv, ay = a01[1] * inv;
    float az = a23[0] * inv, aw = a23[1] * inv;

    // mean over heads (head1 sits at lane^16 within the half)
    ax += __shfl_xor(ax, 16); ay += __shfl_xor(ay, 16);
    az += __shfl_xor(az, 16); aw += __shfl_xor(aw, 16);
    ax *= 0.5f; ay *= 0.5f; az *= 0.5f; aw *= 0.5f;

    if ((lane & 31) < 16) {
        const float4 b4 = *(const float4*)(bias + 4 * li);
        ax += b4.x; ay += b4.y; az += b4.z; aw += b4.w;
        if (applyGelu) { ax = gelu_f(ax); ay = gelu_f(ay); az = gelu_f(az); aw = gelu_f(aw); }
        *(float4*)(Y + (size_t)v * 64 + 4 * li) = make_float4(ax, ay, az, aw);
    }
}

extern "C" void kernel_launch(void* const* d_in, const int* in_sizes, int n_in,
                              void* d_out, int out_size, void* d_ws, size_t ws_size,
                              hipStream_t stream) {
    const float* X     = (const float*)d_in[0];
    const int*   edges = (const int*)d_in[1];
    const float* Wl    = (const float*)d_in[2];
    const float* bl    = (const float*)d_in[3];
    const float* Wr    = (const float*)d_in[4];
    const float* br    = (const float*)d_in[5];
    const float* att   = (const float*)d_in[6];
    const float* bias  = (const float*)d_in[7];

    char* ws = (char*)d_ws;
    __half* XLb = (__half*)ws;                                        // N*128 fp16
    __half* XRb = (__half*)(ws + (size_t)N_NODES * HC * 4);           // N*128 fp16
    float*  Yb  = (float*)(ws + (size_t)N_NODES * HC * 8);            // N*64 f32
    int*    cnt = (int*)(ws + (size_t)N_NODES * HC * 8 + (size_t)N_NODES * 64 * 4);
    int*    tbl = cnt + N_NODES;                                      // N*CAP ints
    unsigned short* WBh  = (unsigned short*)(tbl + (size_t)N_NODES * CAP); // 64 KB
    unsigned short* WBlo = WBh + 32768;                                    // 64 KB

    // wprep also zeroes cnt (grid-stride) -> no separate memset launch
    wprep_kernel<<<128, 256, 0, stream>>>(Wl, Wr, WBh, WBlo, cnt);

    const int agg_grid = ((N_NODES + 1) / 2 * 64 + 255) / 256;        // 2 nodes/wave

    // layer 0: gemm + scatter fused (matrix/mem pipes vs atomic pipe)
    gemm_scatter_kernel<<<FUSED_BLOCKS, 256, 0, stream>>>(
        X, WBh, WBlo, bl, br, XLb, XRb, edges, cnt, tbl, 1);
    aggregate_kernel<<<agg_grid, 256, 0, stream>>>(XLb, XRb, cnt, tbl, att, bias, Yb, 1);
    // layer 1
    gemm_scatter_kernel<<<GEMM_BLOCKS, 256, 0, stream>>>(
        Yb, WBh + 16384, WBlo + 16384, bl + 128, br + 128, XLb, XRb, edges, cnt, tbl, 0);
    aggregate_kernel<<<agg_grid, 256, 0, stream>>>(XLb, XRb, cnt, tbl, att + 128, bias + 64,
                                                   (float*)d_out, 0);
}